// Round 1
// 361.569 us; speedup vs baseline: 1.0357x; 1.0357x over previous
//
#include <hip/hip_runtime.h>
#include <stdint.h>

// LinearDiscriminator: [T,B,H] fp32 -> MLP(1024->100->10->1) -> logsigmoid
// -> masked sum over T -> exp -> [B] fp32.  T=2048 B=32 H=1024.
// v2: 512-thr/128-row blocks, t-interleaved (t = blk + 512k) for load balance;
// W1 double-buffered via global_load_lds_dwordx4 with XOR-swizzled source
// (linear LDS dest, same-involution swizzled ds_read_b128 -> conflict-free);
// enc prefetched 1 chunk ahead; 1 barrier per K-chunk; h1 wave-local swizzled
// LDS (no post-loop barriers); W2 read direct from L2.

#define T_DIM 2048
#define B_DIM 32
#define H_DIM 1024
#define L1_DIM 100
#define L1_PAD 112   // 7 * 16
#define L2_DIM 10
#define L2_PAD 16
#define K2_PAD 128   // layer-2 K padded (100 -> 128)
#define NBLK  512    // 512 blocks x 128 rows = 65536 rows
#define TSLOT 512    // t-stride between a block's 4 t-slots

#define W1B_ELEMS (L1_PAD * H_DIM)   // 114688 bf16
#define W2B_ELEMS (L2_PAD * K2_PAD)  // 2048 bf16
#define PART_OFF_BYTES ((W1B_ELEMS + W2B_ELEMS) * 2)  // partials: fp32 [32][NBLK]

typedef float v4f __attribute__((ext_vector_type(4)));
typedef short s8  __attribute__((ext_vector_type(8)));

static __device__ __forceinline__ unsigned short f2bf(float f) {
    // round-to-nearest-even f32 -> bf16 (inputs finite; no NaN handling needed)
    unsigned int u = __float_as_uint(f);
    u += 0x7fffu + ((u >> 16) & 1u);
    return (unsigned short)(u >> 16);
}

// ---------------- kernel 0: weight convert + pad ----------------
__global__ void convert_weights(const float* __restrict__ W1,
                                const float* __restrict__ W2,
                                unsigned short* __restrict__ wsb) {
    int i = blockIdx.x * 256 + threadIdx.x;
    if (i < W1B_ELEMS) {
        int row = i >> 10, col = i & 1023;
        float v = (row < L1_DIM) ? W1[row * H_DIM + col] : 0.0f;
        wsb[i] = f2bf(v);
    } else {
        int j = i - W1B_ELEMS;
        if (j < W2B_ELEMS) {
            int r = j >> 7, c = j & 127;
            float v = (r < L2_DIM && c < L1_DIM) ? W2[r * L1_DIM + c] : 0.0f;
            wsb[W1B_ELEMS + j] = f2bf(v);
        }
    }
}

// ---------------- kernel 1: main fused MLP ----------------
__global__ __launch_bounds__(512, 4) void mlp_main(
    const float* __restrict__ enc,      // [T][B][H] fp32
    const int*   __restrict__ lenp,     // int32, or int64 (runtime-detected)
    const float* __restrict__ b1,
    const float* __restrict__ b2,
    const float* __restrict__ W3,
    const float* __restrict__ b3,
    const unsigned short* __restrict__ w1b,  // bf16 [112][1024]
    const unsigned short* __restrict__ w2b,  // bf16 [16][128]
    float* __restrict__ partials)            // fp32 [32][NBLK]
{
    // W1 K-chunk double buffer: linear, XOR-swizzled content (14336 B each)
    __shared__ __align__(16) unsigned short bufB[2][L1_PAD * 64];  // 28672 B
    // h1 bf16, [128 rows][128 cols], XOR-swizzled within row (16B chunks)
    __shared__ __align__(16) unsigned short ldsH[128 * 128];       // 32768 B
    __shared__ float ldsPart[4][32];                               // 512 B
    // total 61952 B -> 2 blocks/CU, 16 waves/CU

    const int tid  = threadIdx.x;
    const int blk  = blockIdx.x;
    const int lane = tid & 63;
    const int w    = tid >> 6;    // wave 0..7
    const int m    = lane & 15;
    const int q    = lane >> 4;
    const int mx   = m & 7;

    // lengths: detect int64 (lengths >= 1, so elem0's high word == 0 iff int64)
    const bool is64 = (lenp[1] == 0);

    // t-interleaved mapping: wave pair k = w>>1 handles t = blk + 512k, b-half w&1
    const int slot = w >> 1;                     // 0..3
    const int tA   = blk + TSLOT * slot;
    const int bA   = ((w & 1) << 4) + m;
    const int lenA = is64 ? lenp[2 * bA] : lenp[bA];
    const bool predA   = (tA < lenA);
    const bool waveAct = (__ballot(predA) != 0ull);

    // per-lane constants
    float b1v[7];
#pragma unroll
    for (int nt = 0; nt < 7; ++nt) {
        int n = nt * 16 + m;
        b1v[nt] = (n < L1_DIM) ? b1[n] : 0.0f;
    }
    const float b2v = (m < L2_DIM) ? b2[m] : 0.0f;
    const float w3v = (m < L2_DIM) ? W3[m] : 0.0f;
    const float b3s = b3[0];

    const float* aptr = enc + (size_t)(tA * B_DIM + bA) * H_DIM + (q << 3);

    // zero h1 K-pad chunks (cols 112..127 = chunks 14,15), wave-local rows,
    // stored at swizzled positions so later swizzled reads see zeros
    {
        int r  = (w << 4) + (lane >> 2);
        int c  = 14 + ((lane >> 1) & 1);
        int cl = c ^ (r & 7);
        *(uint2*)&ldsH[(r << 7) + (cl << 3) + ((lane & 1) << 2)] = make_uint2(0u, 0u);
    }

    // stage W1 chunk kc -> bufB[buf]: 14 segments of 1KB; wave w does {w, w+8}.
    // LDS linear pos (r, c_lin) holds global chunk c_g = c_lin ^ (r&7)
    // (pre-swizzled SOURCE + linear gload_lds dest; reads apply same XOR).
    auto stageW1 = [&](int buf, int kc) {
#pragma unroll
        for (int rep = 0; rep < 2; ++rep) {
            const int s = w + (rep << 3);
            if (s < 14) {
                const int idx = (s << 6) + lane;         // chunk index 0..895
                const int r   = idx >> 3;                // W1 row 0..111
                const int cg  = (idx & 7) ^ (r & 7);     // global 16B chunk in tile
                const unsigned short* gsrc =
                    w1b + (r << 10) + (kc << 6) + (cg << 3);
                __builtin_amdgcn_global_load_lds(
                    (const __attribute__((address_space(1))) unsigned int*)gsrc,
                    (__attribute__((address_space(3))) unsigned int*)&bufB[buf][s << 9],
                    16, 0, 0);
            }
        }
    };

    float4 xc0, xc1, xc2, xc3, xn0, xn1, xn2, xn3;
    auto loadX = [&](int kc, float4& a, float4& b, float4& c, float4& d) {
        if (predA) {
            const float* p = aptr + (kc << 6);
            a = *(const float4*)(p);
            b = *(const float4*)(p + 4);
            c = *(const float4*)(p + 32);
            d = *(const float4*)(p + 36);
        } else {
            a = b = c = d = make_float4(0.f, 0.f, 0.f, 0.f);
        }
    };

    v4f acc[7];
#pragma unroll
    for (int nt = 0; nt < 7; ++nt) acc[nt] = (v4f)0.0f;

    // prologue: chunk 0 in flight before first barrier
    stageW1(0, 0);
    loadX(0, xc0, xc1, xc2, xc3);
    xn0 = xn1 = xn2 = xn3 = make_float4(0.f, 0.f, 0.f, 0.f);

    // swizzled read offsets for bufB (shorts): row m, chunk ks*4+q
    const int v0   = ((q ^ mx) << 3);
    const int v1   = (((4 + q) ^ mx) << 3);
    const int mrow = m << 6;

    // ---- layer-1 K loop: 16 chunks of BK=64, 1 barrier/chunk, dbuf ----
#pragma unroll
    for (int kc = 0; kc < 16; ++kc) {
        const int cur = kc & 1;
        // barrier: own vmem drained on entry -> bufB[cur] staged by all waves;
        // all waves done reading bufB[cur^1] (compute kc-1) -> safe to restage it
        __syncthreads();
        if (kc < 15) {
            stageW1(cur ^ 1, kc + 1);              // in flight until next barrier
            loadX(kc + 1, xn0, xn1, xn2, xn3);     // enc prefetch, ditto
        }
        if (waveAct) {
            const unsigned short* bb = &bufB[cur][mrow];
#pragma unroll
            for (int ks = 0; ks < 2; ++ks) {
                const float4 lo = ks ? xc2 : xc0;
                const float4 hi = ks ? xc3 : xc1;
                s8 af;
                af[0] = (short)f2bf(lo.x); af[1] = (short)f2bf(lo.y);
                af[2] = (short)f2bf(lo.z); af[3] = (short)f2bf(lo.w);
                af[4] = (short)f2bf(hi.x); af[5] = (short)f2bf(hi.y);
                af[6] = (short)f2bf(hi.z); af[7] = (short)f2bf(hi.w);
                const int vo = ks ? v1 : v0;
#pragma unroll
                for (int nt = 0; nt < 7; ++nt) {
                    const s8 bf = *(const s8*)(bb + (nt << 10) + vo);
                    acc[nt] = __builtin_amdgcn_mfma_f32_16x16x32_bf16(
                        af, bf, acc[nt], 0, 0, 0);
                }
            }
        }
        xc0 = xn0; xc1 = xn1; xc2 = xn2; xc3 = xn3;
    }

    // ---- h1 = relu(acc + b1) -> ldsH (swizzled; rows are wave-local,
    // so no barrier needed between write and layer-2 read) ----
#pragma unroll
    for (int nt = 0; nt < 7; ++nt) {
#pragma unroll
        for (int reg = 0; reg < 4; ++reg) {
            const float h  = fmaxf(acc[nt][reg] + b1v[nt], 0.0f);
            const int row  = (w << 4) + (q << 2) + reg;
            const int col  = (nt << 4) + m;
            const int cl   = (col >> 3) ^ (row & 7);
            ldsH[(row << 7) + (cl << 3) + (col & 7)] = f2bf(h);
        }
    }

    // ---- layer-2 MFMA: rows wave-local, K=128; W2 direct from L2 ----
    v4f acc2 = (v4f)0.0f;
    {
        const unsigned short* hb = &ldsH[((w << 4) + m) << 7];  // row&7 == mx
#pragma unroll
        for (int ks = 0; ks < 4; ++ks) {
            const int cl = ((ks << 2) + q) ^ mx;
            const s8 a2  = *(const s8*)(hb + (cl << 3));
            const s8 b2f = *(const s8*)(w2b + (m << 7) + (ks << 5) + (q << 3));
            acc2 = __builtin_amdgcn_mfma_f32_16x16x32_bf16(a2, b2f, acc2, 0, 0, 0);
        }
    }

    // ---- layer 3 + logsigmoid ----
    v4f z;
#pragma unroll
    for (int reg = 0; reg < 4; ++reg) {
        const float y2 = fmaxf(acc2[reg] + b2v, 0.0f);   // col j = m
        z[reg] = y2 * w3v;
    }
#pragma unroll
    for (int msk = 1; msk < 16; msk <<= 1) {
#pragma unroll
        for (int reg = 0; reg < 4; ++reg)
            z[reg] += __shfl_xor(z[reg], msk, 16);
    }
    if (m == 0) {
#pragma unroll
        for (int reg = 0; reg < 4; ++reg) {
            const int rowLocal = (q << 2) + reg;          // row in wave tile
            const int bC   = ((w & 1) << 4) + rowLocal;   // its b
            const int lenC = is64 ? lenp[2 * bC] : lenp[bC];
            const float logit = z[reg] + b3s;
            const float logp  = fminf(logit, 0.0f) - log1pf(__expf(-fabsf(logit)));
            ldsPart[slot][bC] = (tA < lenC) ? logp : 0.0f;
        }
    }
    __syncthreads();
    if (tid < 32)
        partials[tid * NBLK + blk] =
            ldsPart[0][tid] + ldsPart[1][tid] + ldsPart[2][tid] + ldsPart[3][tid];
}

// ---------------- kernel 2: reduce + exp ----------------
__global__ void finalize(const float* __restrict__ partials,
                         float* __restrict__ out) {
    const int b = blockIdx.x;
    const int tid = threadIdx.x;
    float s = 0.0f;
    for (int i = tid; i < NBLK; i += 256) s += partials[b * NBLK + i];
#pragma unroll
    for (int off = 32; off > 0; off >>= 1) s += __shfl_down(s, off, 64);
    __shared__ float red[4];
    if ((tid & 63) == 0) red[tid >> 6] = s;
    __syncthreads();
    if (tid == 0) out[b] = expf(red[0] + red[1] + red[2] + red[3]);
}

extern "C" void kernel_launch(void* const* d_in, const int* in_sizes, int n_in,
                              void* d_out, int out_size, void* d_ws, size_t ws_size,
                              hipStream_t stream) {
    const float* enc = (const float*)d_in[0];
    const int*   len = (const int*)d_in[1];
    const float* W1  = (const float*)d_in[2];
    const float* b1  = (const float*)d_in[3];
    const float* W2  = (const float*)d_in[4];
    const float* b2  = (const float*)d_in[5];
    const float* W3  = (const float*)d_in[6];
    const float* b3  = (const float*)d_in[7];

    unsigned short* wsb = (unsigned short*)d_ws;
    float* partials = (float*)((char*)d_ws + PART_OFF_BYTES);
    float* out = (float*)d_out;

    convert_weights<<<(W1B_ELEMS + W2B_ELEMS + 255) / 256, 256, 0, stream>>>(W1, W2, wsb);
    mlp_main<<<NBLK, 512, 0, stream>>>(enc, len, b1, b2, W3, b3,
                                       wsb, wsb + W1B_ELEMS, partials);
    finalize<<<B_DIM, 256, 0, stream>>>(partials, out);
}